// Round 1
// 79.204 us; speedup vs baseline: 1.0117x; 1.0117x over previous
//
#include <hip/hip_runtime.h>

#define BBATCH 4
#define NN 1024
#define EE 32

typedef short v8s __attribute__((ext_vector_type(8)));
typedef float v4f __attribute__((ext_vector_type(4)));

__device__ __forceinline__ unsigned short f32_to_bf16(float v) {
    unsigned u = __builtin_bit_cast(unsigned, v);
    u += 0x7fffu + ((u >> 16) & 1u);      // round-to-nearest-even
    return (unsigned short)(u >> 16);
}

// ---------------------------------------------------------------------------
// Prep: fold coords into emb, convert to bf16 (same RNE rounding as before),
// fp32 row norms from the exact fp32 values.  Runs ONCE -> d_ws, replacing
// the per-block full-batch LDS staging that every one of the 256 blocks of
// the old kernel redid (64x redundant per batch).
// 32768 float4 total: grid 128 x 256.
// ---------------------------------------------------------------------------
__global__ __launch_bounds__(256) void prep_kernel(
    const float* __restrict__ emb, const float* __restrict__ coords,
    unsigned short* __restrict__ ybf, float* __restrict__ nrm)
{
    const int g  = blockIdx.x * 256 + threadIdx.x;   // float4 index
    const int r  = g >> 3, qq = g & 7;               // row in [0,4096), quad
    float4 v = ((const float4*)emb)[g];
    if (qq == 0) { v.x += coords[r * 2 + 0]; v.y += coords[r * 2 + 1]; }
    ushort4 h;
    h.x = f32_to_bf16(v.x); h.y = f32_to_bf16(v.y);
    h.z = f32_to_bf16(v.z); h.w = f32_to_bf16(v.w);
    ((ushort4*)ybf)[g] = h;                          // linear [4096][32] bf16
    float p = v.x * v.x + v.y * v.y + v.z * v.z + v.w * v.w;
    #pragma unroll
    for (int off = 1; off < 8; off <<= 1) p += __shfl_xor(p, off, 64);
    if (qq == 0) nrm[r] = p;                         // fp32 norm of exact y
}

// ---------------------------------------------------------------------------
// Main: one block = 16-row strip x all 1024 j of one batch.  A/B fragments
// read straight from global bf16 Y (256 KB/batch -> L2-resident; each wave
// fragment load is a permutation of a contiguous, 16B-aligned 1 KB region ->
// fully coalesced).  No LDS Y, no staging barrier, no swizzle.
// MFMA 16x16x32 bf16; D layout col=lane&15, row=(lane>>4)*4+reg (m89).
// ---------------------------------------------------------------------------
__global__ __launch_bounds__(1024) void fused_kernel(
    const unsigned short* __restrict__ ybf, const float* __restrict__ nrm,
    const int* __restrict__ mask, float* __restrict__ out)
{
    const int bid = blockIdx.x;           // b(2) | istrip(6)
    const int is = bid & 63;
    const int b  = bid >> 6;
    const int tid  = threadIdx.x;
    const int wave = tid >> 6, lane = tid & 63;
    const int m = lane & 15, q = lane >> 4;

    __shared__ float sums_w[16][16];
    __shared__ float total_s[16];
    __shared__ float wred[16];

    const unsigned short* Y  = ybf + (size_t)b * NN * EE;
    const float*          NR = nrm + b * NN;
    const int i0   = is * 16;
    const int irow = i0 + q * 4;          // this lane's 4 output rows

    // A fragment: A[m][k = q*8 + 0..7], contiguous 16B global load (L2 hit)
    const v8s af = *(const v8s*)(Y + (i0 + m) * EE + q * 8);
    float ni[4];
    #pragma unroll
    for (int r = 0; r < 4; ++r) ni[r] = NR[irow + r];

    const int jbase = wave * 64;          // 16 waves cover j = 0..1023
    float    ex[4][4];                    // exp(-sim) masked / exp(sim) neg
    float    s[4] = {0.f, 0.f, 0.f, 0.f};
    unsigned mbits = 0u;

    #pragma unroll
    for (int t = 0; t < 4; ++t) {
        const int j0 = jbase + t * 16;
        const v8s bfv = *(const v8s*)(Y + (j0 + m) * EE + q * 8);
        const float njv = NR[j0 + m];     // column j = j0+m
        int mk[4];
        #pragma unroll
        for (int r = 0; r < 4; ++r)
            mk[r] = mask[((size_t)(b * NN + irow + r) << 10) + j0 + m];
        v4f d = __builtin_amdgcn_mfma_f32_16x16x32_bf16(af, bfv, (v4f){0,0,0,0}, 0, 0, 0);
        #pragma unroll
        for (int r = 0; r < 4; ++r) {     // D row = q*4+r, col = m
            float nn   = ni[r] + njv;
            float ssq  = fmaxf(fmaf(-2.f, d[r], nn), 0.f);
            float dist = __builtin_amdgcn_sqrtf(ssq);
            // sim = 1/(1+exp(dist-5)); fast rcp (~1 ulp, << bf16 error budget)
            float sm   = __builtin_amdgcn_rcpf(1.f + __expf(dist - 5.f));
            // single exp: -sim for masked (phase 2), +sim for negatives (sum)
            const float e = __expf(mk[r] != 0 ? -sm : sm);
            ex[t][r] = e;
            bool negm = (mk[r] != 0) || (irow + r == j0 + m);
            s[r] += negm ? 0.f : e;
            if (mk[r] != 0) mbits |= 1u << (t * 4 + r);
        }
    }

    // per-row totals: 16-lane reduce (over m) -> LDS[wave][row] -> sum 16 waves
    #pragma unroll
    for (int r = 0; r < 4; ++r) {
        float v = s[r];
        #pragma unroll
        for (int off = 8; off > 0; off >>= 1) v += __shfl_down(v, off, 16);
        if (m == 0) sums_w[wave][q * 4 + r] = v;
    }
    __syncthreads();
    if (tid < 16) {
        float tot = 0.f;
        #pragma unroll
        for (int w = 0; w < 16; ++w) tot += sums_w[w][tid];
        total_s[tid] = tot;
    }
    __syncthreads();

    // phase 2: masked pairs, term = log1p(total_i * exp(-sim)); total=0 -> 0
    float tot[4];
    #pragma unroll
    for (int r = 0; r < 4; ++r) tot[r] = total_s[q * 4 + r];
    float acc = 0.f;
    #pragma unroll
    for (int t = 0; t < 4; ++t)
        #pragma unroll
        for (int r = 0; r < 4; ++r) {
            float lg = __logf(fmaf(tot[r], ex[t][r], 1.f));
            acc += ((mbits >> (t * 4 + r)) & 1u) ? lg : 0.f;
        }

    #pragma unroll
    for (int off = 32; off > 0; off >>= 1) acc += __shfl_down(acc, off, 64);
    if (lane == 0) wred[wave] = acc;
    __syncthreads();
    if (tid == 0) {
        float a = 0.f;
        #pragma unroll
        for (int w = 0; w < 16; ++w) a += wred[w];
        atomicAdd(out, a);                // 256 atomics total
    }
}

extern "C" void kernel_launch(void* const* d_in, const int* in_sizes, int n_in,
                              void* d_out, int out_size, void* d_ws, size_t ws_size,
                              hipStream_t stream) {
    const float* emb    = (const float*)d_in[0];
    const float* coords = (const float*)d_in[1];
    const int*   mask   = (const int*)d_in[2];
    float*       out    = (float*)d_out;

    unsigned short* ybf = (unsigned short*)d_ws;                       // 256 KB
    float*          nrv = (float*)((char*)d_ws + BBATCH * NN * EE * 2); // +16 KB

    hipMemsetAsync(out, 0, sizeof(float), stream);   // d_out is 0xAA-poisoned
    prep_kernel<<<(BBATCH * NN * EE / 4) / 256, 256, 0, stream>>>(emb, coords, ybf, nrv);
    fused_kernel<<<BBATCH * (NN / 16), 1024, 0, stream>>>(ybf, nrv, mask, out);
}